// Round 1
// baseline (114.341 us; speedup 1.0000x reference)
//
#include <hip/hip_runtime.h>

#define D_ 128
#define N_ 8192
#define K_ 256

typedef __attribute__((ext_vector_type(4))) float f4;    // 4 fp32
typedef __attribute__((ext_vector_type(8))) int i8v;     // 8 x i32 (32 B fp8 frag)
typedef __attribute__((ext_vector_type(4))) int i4v;     // 4 x i32 (16 B)

// ---------------------------------------------------------------------------
// prep_k: fused prep_x + prep_a(+amu). Flat grid of 512 blocks:
//   blocks 0..255   : X (fp32 [D][N]) -> Xf8 (fp8 [N][D]) transpose + exact
//                     fp32 copy of X into out rows 0..D-1.
//   blocks 256..511 : N_A (fp32 [D][D][K]) -> Af8s (fp8, frag-ordered) +
//                     fused negated amu.
// UNCHANGED from previous round.
__global__ __launch_bounds__(256) void prep_k(
    const float* __restrict__ X, float* __restrict__ out,
    unsigned char* __restrict__ Xf8, const float* __restrict__ NA,
    unsigned char* __restrict__ Af8s, const float* __restrict__ Nmu,
    float* __restrict__ Amut) {
  __shared__ __align__(16) char smem[21568];
  const int t = threadIdx.x;
  const int id = blockIdx.x;

  if (id < 256) {
    // ---------------- prep_x role ----------------
    float (*tile)[65] = (float (*)[65])smem;   // 64 x 65 floats = 16.6 KB
    const int n0 = (id & 127) * 64;
    const int e0 = (id >> 7) * 64;
    const int col = t & 63;
    const int r4 = t >> 6;
    for (int rr = 0; rr < 64; rr += 4) {
      int e = rr + r4;
      float v = X[(size_t)(e0 + e) * N_ + n0 + col];
      tile[e][col] = v;
      out[(size_t)(e0 + e) * N_ + n0 + col] = v;   // exact fp32 copy of X
    }
    __syncthreads();
    const int chunk = t & 15;
    for (int iter = 0; iter < 4; ++iter) {
      int nl = iter * 16 + (t >> 4);
      float v0 = tile[chunk * 4 + 0][nl];
      float v1 = tile[chunk * 4 + 1][nl];
      float v2 = tile[chunk * 4 + 2][nl];
      float v3 = tile[chunk * 4 + 3][nl];
      int pk = __builtin_amdgcn_cvt_pk_fp8_f32(v0, v1, 0, false);
      pk = __builtin_amdgcn_cvt_pk_fp8_f32(v2, v3, pk, true);
      *(int*)&Xf8[(size_t)(n0 + nl) * D_ + e0 + chunk * 4] = pk;
    }
  } else {
    // ---------------- prep_a (+amu) role ----------------
    const int aid = id - 256;
    const int dtl = aid & 7;           // d-tile of 16
    const int c0 = (aid >> 3) * 8;     // 8 c per block (32 groups)
    unsigned char* AT = (unsigned char*)smem;        // [cl][d*136+e], 8*2184=17472 B
    float* mu_s = (float*)(smem + 17472);            // [cl][e], 8*128*4 = 4096 B
    // load mu: cl = t&7, er = t>>3; 4 passes of 32 e
    {
      const int cl = t & 7;
      const int er = t >> 3;
#pragma unroll
      for (int pass = 0; pass < 4; ++pass) {
        int e = pass * 32 + er;
        mu_s[cl * 128 + e] = Nmu[(size_t)e * K_ + c0 + cl];
      }
    }
    // load + convert A: float4 across 4 consecutive c; c4 = t&1, pe = t>>1
    const int c4 = t & 1;
    const int pe = t >> 1;
#pragma unroll 4
    for (int iter = 0; iter < 16; ++iter) {
      int p = iter * 128 + pe;
      int d = p >> 7, e = p & 127;
      float4 v = *(const float4*)&NA[((size_t)(dtl * 16 + d) * D_ + e) * K_ + c0 + c4 * 4];
      int pk0 = __builtin_amdgcn_cvt_pk_fp8_f32(v.x, v.x, 0, false);
      int pk1 = __builtin_amdgcn_cvt_pk_fp8_f32(v.y, v.y, 0, false);
      int pk2 = __builtin_amdgcn_cvt_pk_fp8_f32(v.z, v.z, 0, false);
      int pk3 = __builtin_amdgcn_cvt_pk_fp8_f32(v.w, v.w, 0, false);
      AT[(c4 * 4 + 0) * 2184 + d * 136 + e] = (unsigned char)(pk0 & 0xff);
      AT[(c4 * 4 + 1) * 2184 + d * 136 + e] = (unsigned char)(pk1 & 0xff);
      AT[(c4 * 4 + 2) * 2184 + d * 136 + e] = (unsigned char)(pk2 & 0xff);
      AT[(c4 * 4 + 3) * 2184 + d * 136 + e] = (unsigned char)(pk3 & 0xff);
    }
    __syncthreads();
    // fused amu: 128 entries (16 d x 8 c); negated for the MFMA C-operand
    if (t < 128) {
      const int d_loc = t >> 3;
      const int cl = t & 7;
      const unsigned char* row = &AT[cl * 2184 + d_loc * 136];
      const float* mr = &mu_s[cl * 128];
      float s = 0.f;
#pragma unroll
      for (int j = 0; j < 16; ++j) {             // 16 x int2 (8 e each)
        int2 v = *(const int2*)(row + j * 8);
        const int e0 = j * 8;
        s += __builtin_amdgcn_cvt_f32_fp8(v.x, 0) * mr[e0 + 0];
        s += __builtin_amdgcn_cvt_f32_fp8(v.x, 1) * mr[e0 + 1];
        s += __builtin_amdgcn_cvt_f32_fp8(v.x, 2) * mr[e0 + 2];
        s += __builtin_amdgcn_cvt_f32_fp8(v.x, 3) * mr[e0 + 3];
        s += __builtin_amdgcn_cvt_f32_fp8(v.y, 0) * mr[e0 + 4];
        s += __builtin_amdgcn_cvt_f32_fp8(v.y, 1) * mr[e0 + 5];
        s += __builtin_amdgcn_cvt_f32_fp8(v.y, 2) * mr[e0 + 6];
        s += __builtin_amdgcn_cvt_f32_fp8(v.y, 3) * mr[e0 + 7];
      }
      Amut[(size_t)(c0 + cl) * D_ + dtl * 16 + d_loc] = -s;
    }
    // write phase: 16 units (ucl 0..7, h 0..1), each one wave x 16 B per lane
    const int w = t >> 6, L = t & 63, q = L >> 4, m = L & 15;
#pragma unroll
    for (int it = 0; it < 4; ++it) {
      int u = w + it * 4;                 // 0..15
      int ucl = u >> 1, h = u & 1;
      const unsigned char* base = AT + ucl * 2184 + m * 136 + q * 32 + h * 16;
      unsigned long long lo = *(const unsigned long long*)(base);
      unsigned long long hi = *(const unsigned long long*)(base + 8);
      ulonglong2 val; val.x = lo; val.y = hi;
      *(ulonglong2*)(Af8s + (size_t)(c0 + ucl) * 16384 + dtl * 2048 + h * 1024 + L * 16) = val;
    }
  }
}

// ---------------------------------------------------------------------------
// main (MX-fp8, K=128 per instruction): sq[c][n] = sum_d (sum_e A X - Amu)^2
// Flat grid 1024, block 256 (4 waves). NEW this round: bijective XCD-aware
// block remap. Af8s is exactly 4 MiB (= one XCD's whole L2); the old 2D grid
// spread all 32 c-groups across every XCD, so each per-XCD L2 had to hold the
// entire Af8s + Xf8 + sqws stream -> thrash to L3 at ~7.4 TB/s of A-reuse
// traffic. Remap: XCD j (id&7) owns c-groups [j*4, j*4+4) -> per-XCD A
// working set 512 KB (8x smaller), L2-resident.
//   id -> xcd = id&7, s = id>>3;  y = xcd*4 + (s&3) (c-group), x = s>>2 (n-tile)
// Bijective over [0,1024). Compute body UNCHANGED (verified ~80% of the
// 14.7 us MX floor).
__global__ __launch_bounds__(256, 4) void main_k(
    const unsigned char* __restrict__ Af8s, const unsigned char* __restrict__ Xf8,
    const float* __restrict__ Amut, float* __restrict__ sqws) {
  __shared__ unsigned char A0s[16384];
  __shared__ unsigned char A1s[16384];
  __shared__ float amus[2][D_];
  const int t = threadIdx.x;
  const int w = t >> 6;
  const int L = t & 63;
  const int m = L & 15;
  const int q = L >> 4;

  const int id = blockIdx.x;
  const int xcd = id & 7;
  const int s = id >> 3;
  const int yb = xcd * 4 + (s & 3);   // c-group 0..31 (4 per XCD)
  const int xb = s >> 2;              // n-tile 0..31
  const int n0 = xb * 256;
  const int c0 = yb * 8;

  // persistent X B-frags: lane holds n = n0+w*64+jt*16+m, k = q*32 + [0..31] (32 B)
  i8v xf[4];
#pragma unroll
  for (int jt = 0; jt < 4; ++jt)
    xf[jt] = *(const i8v*)(Xf8 + (size_t)(n0 + w * 64 + jt * 16 + m) * D_ + q * 32);

  const unsigned char* pl = Af8s + (size_t)c0 * 16384;

#define STAGE(SRC, DST)                                                          \
  {                                                                              \
    _Pragma("unroll")                                                            \
    for (int it_ = 0; it_ < 4; ++it_)                                            \
      __builtin_amdgcn_global_load_lds(                                          \
          (const unsigned int*)((SRC) + (it_ * 256 + t) * 16),                   \
          (unsigned int*)((DST) + (it_ * 256 + w * 64) * 16), 16, 0, 0);         \
  }

  STAGE(pl, A0s);
  if (t < 32)
    __builtin_amdgcn_global_load_lds((const unsigned int*)(Amut + (size_t)c0 * D_ + t * 4),
                                     (unsigned int*)&amus[0][0], 16, 0, 0);

  auto compute = [&](const unsigned char* buf, const float* amurow, int c) {
    float ss0 = 0.f, ss1 = 0.f, ss2 = 0.f, ss3 = 0.f;
#pragma unroll
    for (int dtl = 0; dtl < 8; ++dtl) {
      i4v lo = *(const i4v*)(buf + dtl * 2048 + L * 16);          // k = q*32+0..15
      i4v hi = *(const i4v*)(buf + dtl * 2048 + 1024 + L * 16);   // k = q*32+16..31
      i8v a;
      a[0] = lo[0]; a[1] = lo[1]; a[2] = lo[2]; a[3] = lo[3];
      a[4] = hi[0]; a[5] = hi[1]; a[6] = hi[2]; a[7] = hi[3];
      f4 camu = *(const f4*)&amurow[dtl * 16 + q * 4];   // = -Amu slice
#pragma unroll
      for (int jt = 0; jt < 4; ++jt) {
        f4 acc = __builtin_amdgcn_mfma_scale_f32_16x16x128_f8f6f4(
            a, xf[jt], camu, 0, 0, 0, 0x7f7f7f7f, 0, 0x7f7f7f7f);
        float sj = acc[0] * acc[0] + acc[1] * acc[1] + acc[2] * acc[2] + acc[3] * acc[3];
        if (jt == 0) ss0 += sj; else if (jt == 1) ss1 += sj;
        else if (jt == 2) ss2 += sj; else ss3 += sj;
      }
    }
    ss0 += __shfl_xor(ss0, 16, 64);  ss0 += __shfl_xor(ss0, 32, 64);
    ss1 += __shfl_xor(ss1, 16, 64);  ss1 += __shfl_xor(ss1, 32, 64);
    ss2 += __shfl_xor(ss2, 16, 64);  ss2 += __shfl_xor(ss2, 32, 64);
    ss3 += __shfl_xor(ss3, 16, 64);  ss3 += __shfl_xor(ss3, 32, 64);
    float sel = (q == 0) ? ss0 : (q == 1) ? ss1 : (q == 2) ? ss2 : ss3;
    sqws[(size_t)c * N_ + n0 + w * 64 + L] = sel;
  };

  for (int ci2 = 0; ci2 < 4; ++ci2) {
    const int cA = c0 + ci2 * 2;
    __syncthreads();   // drains stage of plane(cA) into A0s
    STAGE(pl + (size_t)(ci2 * 2 + 1) * 16384, A1s);
    if (t < 32)
      __builtin_amdgcn_global_load_lds(
          (const unsigned int*)(Amut + (size_t)(cA + 1) * D_ + t * 4),
          (unsigned int*)&amus[1][0], 16, 0, 0);
    compute(A0s, &amus[0][0], cA);

    __syncthreads();   // drains stage of plane(cA+1) into A1s
    if (ci2 < 3) {
      STAGE(pl + (size_t)(ci2 * 2 + 2) * 16384, A0s);
      if (t < 32)
        __builtin_amdgcn_global_load_lds(
            (const unsigned int*)(Amut + (size_t)(cA + 2) * D_ + t * 4),
            (unsigned int*)&amus[0][0], 16, 0, 0);
    }
    compute(A1s, &amus[1][0], cA + 1);
  }
#undef STAGE
}

// ---------------------------------------------------------------------------
// softmax v2: 32-n tiles (256 blocks), float4 loads (128-B segments per c-row),
// exp values in registers. grid (N/32), block 256: nl = t&31, cg = t>>5 (8 x 32 c).
// UNCHANGED.
__global__ __launch_bounds__(256) void softmax_k(const float* __restrict__ sqws,
                                                 const float* __restrict__ gptr,
                                                 float* __restrict__ out) {
  __shared__ float s_ld[256][36];   // pad 36: f4-aligned rows, conflict-free reads
  __shared__ float red[8][32];
  __shared__ float red2[8][32];
  const int t = threadIdx.x;
  const int n0 = blockIdx.x * 32;
  const float gamma = *gptr;
#pragma unroll
  for (int it = 0; it < 8; ++it) {
    int f = it * 256 + t;
    int c = f >> 3, nq = f & 7;
    *(float4*)&s_ld[c][nq * 4] = *(const float4*)&sqws[(size_t)c * N_ + n0 + nq * 4];
  }
  __syncthreads();
  const int nl = t & 31;
  const int cg = t >> 5;
  float mxp = -1e30f;
#pragma unroll
  for (int cc = 0; cc < 32; ++cc)
    mxp = fmaxf(mxp, gamma * s_ld[cg * 32 + cc][nl]);
  red[cg][nl] = mxp;
  __syncthreads();
  float mx = red[0][nl];
#pragma unroll
  for (int g2 = 1; g2 < 8; ++g2) mx = fmaxf(mx, red[g2][nl]);
  float ex[32];
  float z = 0.f;
#pragma unroll
  for (int cc = 0; cc < 32; ++cc) {
    ex[cc] = __expf(gamma * s_ld[cg * 32 + cc][nl] - mx);
    z += ex[cc];
  }
  red2[cg][nl] = z;
  __syncthreads();
  float zz = red2[0][nl];
#pragma unroll
  for (int g2 = 1; g2 < 8; ++g2) zz += red2[g2][nl];
  float rz = 1.f / zz;
#pragma unroll
  for (int cc = 0; cc < 32; ++cc)
    out[(size_t)(D_ + cg * 32 + cc) * N_ + n0 + nl] = ex[cc] * rz;
}

// ---------------------------------------------------------------------------
extern "C" void kernel_launch(void* const* d_in, const int* in_sizes, int n_in,
                              void* d_out, int out_size, void* d_ws, size_t ws_size,
                              hipStream_t stream) {
  const float* X   = (const float*)d_in[0];
  const float* NA  = (const float*)d_in[1];
  const float* Nmu = (const float*)d_in[2];
  const float* g   = (const float*)d_in[3];
  float* out = (float*)d_out;
  char* ws = (char*)d_ws;

  unsigned char* Xf8  = (unsigned char*)(ws);                  // 1 MB
  unsigned char* Af8s = (unsigned char*)(ws + 1048576);        // 4.19 MB
  float* Amut         = (float*)(ws + 5242880);                // 128 KB
  float* sqws         = (float*)(ws + 5373952);                // 8.39 MB

  hipLaunchKernelGGL(prep_k, dim3(512), dim3(256), 0, stream,
                     X, out, Xf8, NA, Af8s, Nmu, Amut);
  hipLaunchKernelGGL(main_k, dim3(1024), dim3(256), 0, stream,
                     Af8s, Xf8, Amut, sqws);
  hipLaunchKernelGGL(softmax_k, dim3(N_ / 32), dim3(256), 0, stream, sqws, g, out);
}